// Round 3
// baseline (408.148 us; speedup 1.0000x reference)
//
#include <hip/hip_runtime.h>

typedef int v4i  __attribute__((ext_vector_type(4)));
typedef int v16i __attribute__((ext_vector_type(16)));

__device__ __forceinline__ int pack4i(int a, int b, int c, int d) {
  return (a & 255) | ((b & 255) << 8) | ((c & 255) << 16) | ((d & 255) << 24);
}

// ---------------------------------------------------------------------------
// Pack (W + E) -> int8, transposed Bt[n][k] (row stride K bytes).
// Tile: 64 n x 256 k per block, 256 threads. Zero-pads n >= N rows.
// ---------------------------------------------------------------------------
__device__ void pack_tile(const int* __restrict__ W, const int* __restrict__ E,
                          char* __restrict__ Bt, int K, int N,
                          int nx, int ky, char* lin) {
  const int t = threadIdx.x;
  const int n0 = nx * 64, k0 = ky * 256;
  {
    const int kk = t >> 2, c = t & 3;
    for (int p = 0; p < 4; ++p) {
      const int k = kk + (p << 6);
      const long grow = (long)(k0 + k) * N;
      #pragma unroll
      for (int i = 0; i < 4; ++i) {
        const int nl = (c << 4) + (i << 2);
        const int ng = n0 + nl;
        int a0, a1, a2, a3;
        if (ng + 3 < N) {
          int4 wv = *(const int4*)(W + grow + ng);
          int4 ev = *(const int4*)(E + grow + ng);
          a0 = wv.x + ev.x; a1 = wv.y + ev.y; a2 = wv.z + ev.z; a3 = wv.w + ev.w;
        } else {
          a0 = (ng + 0 < N) ? W[grow + ng + 0] + E[grow + ng + 0] : 0;
          a1 = (ng + 1 < N) ? W[grow + ng + 1] + E[grow + ng + 1] : 0;
          a2 = (ng + 2 < N) ? W[grow + ng + 2] + E[grow + ng + 2] : 0;
          a3 = (ng + 3 < N) ? W[grow + ng + 3] + E[grow + ng + 3] : 0;
        }
        *(int*)(lin + k * 68 + nl) = pack4i(a0, a1, a2, a3);
      }
    }
  }
  __syncthreads();
  {
    const int n = t & 63, kq = t >> 6;
    char* dst = Bt + (long)(n0 + n) * K + k0 + (kq << 6);
    int outv[16];
    #pragma unroll
    for (int g = 0; g < 16; ++g) {
      const int k = (kq << 6) + (g << 2);
      outv[g] = pack4i(lin[(k + 0) * 68 + n], lin[(k + 1) * 68 + n],
                       lin[(k + 2) * 68 + n], lin[(k + 3) * 68 + n]);
    }
    #pragma unroll
    for (int g = 0; g < 4; ++g)
      *(int4*)(dst + (g << 4)) =
          make_int4(outv[g * 4], outv[g * 4 + 1], outv[g * 4 + 2], outv[g * 4 + 3]);
  }
}

__global__ __launch_bounds__(256) void pack_all_kernel(
    const int* W1, const int* E1, char* Bt1,
    const int* W2, const int* E2, char* Bt2,
    const int* W3, const int* E3, char* Bt3,
    const int* b1, const int* eb1, int* bs1,
    const int* b2, const int* eb2, int* bs2,
    const int* b3, const int* eb3, int* bs3) {
  __shared__ __align__(16) char lin[256 * 68];
  const int bid = blockIdx.x;
  if (bid < 192) {
    pack_tile(W1, E1, Bt1, 3072, 1024, bid % 16, bid / 16, lin);
  } else if (bid < 256) {
    const int l = bid - 192;
    pack_tile(W2, E2, Bt2, 1024, 1024, l % 16, l / 16, lin);
  } else if (bid < 264) {
    const int l = bid - 256;
    pack_tile(W3, E3, Bt3, 1024, 100, l & 1, l >> 1, lin);
  } else {
    const int t = threadIdx.x;
    for (int i = t; i < 1024; i += 256) {
      bs1[i] = b1[i] + eb1[i];
      bs2[i] = b2[i] + eb2[i];
    }
    for (int i = t; i < 128; i += 256)
      bs3[i] = (i < 100) ? (b3[i] + eb3[i]) : 0;
  }
}

// ---------------------------------------------------------------------------
// GEMM: C = trunc_i8(A @ Bt^T + bsum [+ H]) ; 128x128 tile, BK=64, 256 thr.
// Software-pipelined: 2-stage LDS double buffer, global prefetch into regs,
// ONE barrier per K-iter (writes go to the buffer whose reads were fenced by
// the previous barrier).
// AMODE 0: A is int32 [M][K]; AMODE 1: A is int8 [M][K].
// ---------------------------------------------------------------------------
template<int AMODE, bool DO_HADD, bool DO_I8OUT, bool DO_IOUT, bool DO_MASK>
__global__ __launch_bounds__(256, 2) void gemm_kernel(
    const void* __restrict__ Asrc, const char* __restrict__ Btg,
    const int* __restrict__ bsum, const int* __restrict__ Hadd,
    char* __restrict__ A8out, int* __restrict__ Iout,
    const int K, const int ldC, const int nvalid) {
  // stage layout: As [128][80] (10240 B) + Bs [128][80] (10240 B) = 20480 B
  __shared__ __align__(16) char smem[40960];

  const int t = threadIdx.x;
  const int mt = blockIdx.x & 63;   // same-A blocks land on same XCD (bid%8 const)
  const int nt = blockIdx.x >> 6;
  const long m0 = (long)mt << 7;
  const int n0 = nt << 7;

  const int lane = t & 63, w = t >> 6;
  const int wm = w & 1, wn = w >> 1;
  const int lc = lane & 31, hg = lane >> 5;

  v16i acc[2][2] = {};

  const int sm = t >> 1, sh = t & 1;
  const long arow = (m0 + sm) * (long)K + sh * 32;   // elements (int or byte)
  const char* Brow = Btg + (long)(n0 + sm) * K + sh * 32;
  const int soff = sm * 80 + sh * 32;                // LDS write offset (A and B)

  const int abo = (wm * 64 + lc) * 80 + hg * 16;     // LDS read offsets
  const int bbo = (wn * 64 + lc) * 80 + hg * 16;

  int4 ar[8];            // prefetch regs: AMODE0 uses 8, AMODE1 uses 2
  int4 br[2];

  auto LOAD = [&](int kb) {
    if (AMODE == 0) {
      const int* Ar = (const int*)Asrc + arow + kb;
      #pragma unroll
      for (int i = 0; i < 8; ++i) ar[i] = *(const int4*)(Ar + (i << 2));
    } else {
      const char* Ar = (const char*)Asrc + arow + kb;
      ar[0] = *(const int4*)(Ar);
      ar[1] = *(const int4*)(Ar + 16);
    }
    br[0] = *(const int4*)(Brow + kb);
    br[1] = *(const int4*)(Brow + kb + 16);
  };
  auto STORE = [&](int stage) {
    char* As_ = smem + stage * 20480;
    char* Bs_ = As_ + 10240;
    if (AMODE == 0) {
      int d[8];
      #pragma unroll
      for (int i = 0; i < 8; ++i) d[i] = pack4i(ar[i].x, ar[i].y, ar[i].z, ar[i].w);
      *(int4*)(As_ + soff)      = make_int4(d[0], d[1], d[2], d[3]);
      *(int4*)(As_ + soff + 16) = make_int4(d[4], d[5], d[6], d[7]);
    } else {
      *(int4*)(As_ + soff)      = ar[0];
      *(int4*)(As_ + soff + 16) = ar[1];
    }
    *(int4*)(Bs_ + soff)      = br[0];
    *(int4*)(Bs_ + soff + 16) = br[1];
  };

  const int kiters = K >> 6;
  LOAD(0);
  STORE(0);
  __syncthreads();

  for (int kt = 0; kt < kiters; ++kt) {
    if (kt + 1 < kiters) LOAD((kt + 1) << 6);   // in flight during MFMA
    const char* base = smem + (kt & 1) * 20480;
    const char* Ab = base + abo;
    const char* Bb = base + 10240 + bbo;
    #pragma unroll
    for (int ks = 0; ks < 2; ++ks) {
      v4i a0 = *(const v4i*)(Ab + ks * 32);
      v4i a1 = *(const v4i*)(Ab + 32 * 80 + ks * 32);
      v4i b0 = *(const v4i*)(Bb + ks * 32);
      v4i b1 = *(const v4i*)(Bb + 32 * 80 + ks * 32);
      acc[0][0] = __builtin_amdgcn_mfma_i32_32x32x32_i8(a0, b0, acc[0][0], 0, 0, 0);
      acc[0][1] = __builtin_amdgcn_mfma_i32_32x32x32_i8(a0, b1, acc[0][1], 0, 0, 0);
      acc[1][0] = __builtin_amdgcn_mfma_i32_32x32x32_i8(a1, b0, acc[1][0], 0, 0, 0);
      acc[1][1] = __builtin_amdgcn_mfma_i32_32x32x32_i8(a1, b1, acc[1][1], 0, 0, 0);
    }
    if (kt + 1 < kiters) {
      STORE((kt + 1) & 1);   // buffer fenced by previous barrier
      __syncthreads();
    }
  }

  // Epilogue. C/D layout: col = lane&31, row = (reg&3) + 8*(reg>>2) + 4*hg.
  if (DO_I8OUT) __syncthreads();   // smem about to be reused as transpose buffer
  const int bsv[2] = { bsum[n0 + wn * 64 + lc], bsum[n0 + wn * 64 + 32 + lc] };
  #pragma unroll
  for (int tm = 0; tm < 2; ++tm) {
    #pragma unroll
    for (int tn = 0; tn < 2; ++tn) {
      const int gcl = wn * 64 + tn * 32 + lc;
      const long gc = n0 + gcl;
      #pragma unroll
      for (int r = 0; r < 16; ++r) {
        const int lrow = wm * 64 + tm * 32 + (hg << 2) + (r & 3) + ((r >> 2) << 3);
        const long gm = m0 + lrow;
        int v = acc[tm][tn][r] + bsv[tn];
        if (DO_HADD) v += Hadd[gm * 1024 + gc];
        const int b8 = (int)(signed char)v;   // mod-256 truncate, sign-extend
        if (DO_I8OUT) smem[lrow * 144 + gcl] = (char)b8;
        if (DO_IOUT) {
          if (!DO_MASK || gcl < nvalid)
            Iout[gm * ldC + gc] = b8;          // d_out read back as int32
        }
      }
    }
  }
  if (DO_I8OUT) {
    __syncthreads();
    const char* src = smem + sm * 144 + sh * 64;
    char* dst = A8out + ((m0 + sm) << 10) + n0 + sh * 64;
    #pragma unroll
    for (int g = 0; g < 4; ++g)
      *(int4*)(dst + (g << 4)) = *(const int4*)(src + (g << 4));
  }
}

// ---------------------------------------------------------------------------
// Layer 3: 32x128 tile (256 blocks for 8192 rows), K=1024, same pipelining.
// A = h2 as int32 from d_out; Bt3 zero-padded to 128 rows; mask cols >= 100.
// ---------------------------------------------------------------------------
__global__ __launch_bounds__(256, 2) void gemm3_kernel(
    const int* __restrict__ h2, const char* __restrict__ Btg,
    const int* __restrict__ bsum, int* __restrict__ Iout) {
  // stage: As [32][80] (2560) + Bs [128][80] (10240) = 12800 B
  __shared__ __align__(16) char smem[25600];
  const int t = threadIdx.x;
  const int m0 = blockIdx.x << 5;
  const int lane = t & 63, w = t >> 6;
  const int lc = lane & 31, hg = lane >> 5;
  v16i acc = {};

  const int am = t >> 3, ah = t & 7;                 // 32 rows x 8 thr, 8 ints
  const long arow = (long)(m0 + am) * 1024 + ah * 8;
  const int aoff = am * 80 + ah * 8;
  const int bm = t >> 1, bh = t & 1;                 // 128 rows x 2 thr, 32 B
  const char* Brow = Btg + (long)bm * 1024 + bh * 32;
  const int boff = bm * 80 + bh * 32;

  int4 ar[2]; int4 br[2];
  auto LOAD = [&](int kb) {
    const int* Ar = h2 + arow + kb;
    ar[0] = *(const int4*)(Ar);
    ar[1] = *(const int4*)(Ar + 4);
    br[0] = *(const int4*)(Brow + kb);
    br[1] = *(const int4*)(Brow + kb + 16);
  };
  auto STORE = [&](int stage) {
    char* As_ = smem + stage * 12800;
    char* Bs_ = As_ + 2560;
    int2 d;
    d.x = pack4i(ar[0].x, ar[0].y, ar[0].z, ar[0].w);
    d.y = pack4i(ar[1].x, ar[1].y, ar[1].z, ar[1].w);
    *(int2*)(As_ + aoff) = d;
    *(int4*)(Bs_ + boff)      = br[0];
    *(int4*)(Bs_ + boff + 16) = br[1];
  };

  LOAD(0); STORE(0); __syncthreads();
  for (int kt = 0; kt < 16; ++kt) {
    if (kt + 1 < 16) LOAD((kt + 1) << 6);
    const char* base = smem + (kt & 1) * 12800;
    const char* Ab = base + lc * 80 + hg * 16;
    const char* Bb = base + 2560 + (w * 32 + lc) * 80 + hg * 16;
    #pragma unroll
    for (int ks = 0; ks < 2; ++ks) {
      v4i a = *(const v4i*)(Ab + ks * 32);
      v4i b = *(const v4i*)(Bb + ks * 32);
      acc = __builtin_amdgcn_mfma_i32_32x32x32_i8(a, b, acc, 0, 0, 0);
    }
    if (kt + 1 < 16) { STORE((kt + 1) & 1); __syncthreads(); }
  }

  const int gcl = w * 32 + lc;
  if (gcl < 100) {
    const int bs = bsum[gcl];
    #pragma unroll
    for (int r = 0; r < 16; ++r) {
      const int row = (r & 3) + ((r >> 2) << 3) + (hg << 2);
      Iout[(long)(m0 + row) * 100 + gcl] = (int)(signed char)(acc[r] + bs);
    }
  }
}

// ---------------------------------------------------------------------------
// ws layout (12.7 MB): Bt1 | Bt2 | Bt3 | bs1 | bs2 | bs3 | A2
// ---------------------------------------------------------------------------
extern "C" void kernel_launch(void* const* d_in, const int* in_sizes, int n_in,
                              void* d_out, int out_size, void* d_ws, size_t ws_size,
                              hipStream_t stream) {
  (void)in_sizes; (void)n_in; (void)out_size; (void)ws_size;
  const int* W1  = (const int*)d_in[0];
  const int* b1  = (const int*)d_in[1];
  const int* W2  = (const int*)d_in[2];
  const int* b2  = (const int*)d_in[3];
  const int* W3  = (const int*)d_in[4];
  const int* b3  = (const int*)d_in[5];
  const int* E1  = (const int*)d_in[6];
  const int* eb1 = (const int*)d_in[7];
  const int* E2  = (const int*)d_in[8];
  const int* eb2 = (const int*)d_in[9];
  const int* E3  = (const int*)d_in[10];
  const int* eb3 = (const int*)d_in[11];
  const int* X   = (const int*)d_in[12];   // [8192][3072] int32
  const int* H   = (const int*)d_in[13];   // [8192][1024] int32
  int* out = (int*)d_out;                  // h2 [8192*1024] then out [8192*100]

  char* ws  = (char*)d_ws;
  char* Bt1 = ws;                          // 3,145,728
  char* Bt2 = Bt1 + 3145728;               // 1,048,576
  char* Bt3 = Bt2 + 1048576;               //   131,072 (rows 100..127 zeroed)
  int*  bs1 = (int*)(Bt3 + 131072);        // 1024 ints
  int*  bs2 = bs1 + 1024;                  // 1024 ints
  int*  bs3 = bs2 + 1024;                  //  128 ints
  char* A2  = (char*)(bs3 + 128);          // 8,388,608 int8

  pack_all_kernel<<<dim3(265), dim3(256), 0, stream>>>(
      W1, E1, Bt1, W2, E2, Bt2, W3, E3, Bt3,
      b1, eb1, bs1, b2, eb2, bs2, b3, eb3, bs3);

  // Layer 1: i2c fused with hiddens-add -> A2 (int8)
  gemm_kernel<0, true, true, false, false><<<dim3(512), dim3(256), 0, stream>>>(
      X, Bt1, bs1, H, A2, nullptr, 3072, 0, 1024);

  // Layer 2: h2 -> d_out (int32)
  gemm_kernel<1, false, false, true, false><<<dim3(512), dim3(256), 0, stream>>>(
      A2, Bt2, bs2, nullptr, nullptr, out, 1024, 1024, 1024);

  // Layer 3: reads h2 from d_out (int32), writes out region (int32)
  gemm3_kernel<<<dim3(256), dim3(256), 0, stream>>>(
      out, Bt3, bs3, out + 8388608);
}

// Round 4
// 400.197 us; speedup vs baseline: 1.0199x; 1.0199x over previous
//
#include <hip/hip_runtime.h>

typedef int v4i  __attribute__((ext_vector_type(4)));
typedef int v16i __attribute__((ext_vector_type(16)));

__device__ __forceinline__ int pack4i(int a, int b, int c, int d) {
  return (a & 255) | ((b & 255) << 8) | ((c & 255) << 16) | ((d & 255) << 24);
}

// ---------------------------------------------------------------------------
// Pack (W + E) -> int8, transposed Bt[n][k] (row stride K bytes).
// Tile: 64 n x 256 k per block, 256 threads. Zero-pads n >= N rows.
// ---------------------------------------------------------------------------
__device__ void pack_tile(const int* __restrict__ W, const int* __restrict__ E,
                          char* __restrict__ Bt, int K, int N,
                          int nx, int ky, char* lin) {
  const int t = threadIdx.x;
  const int n0 = nx * 64, k0 = ky * 256;
  {
    const int kk = t >> 2, c = t & 3;
    for (int p = 0; p < 4; ++p) {
      const int k = kk + (p << 6);
      const long grow = (long)(k0 + k) * N;
      #pragma unroll
      for (int i = 0; i < 4; ++i) {
        const int nl = (c << 4) + (i << 2);
        const int ng = n0 + nl;
        int a0, a1, a2, a3;
        if (ng + 3 < N) {
          int4 wv = *(const int4*)(W + grow + ng);
          int4 ev = *(const int4*)(E + grow + ng);
          a0 = wv.x + ev.x; a1 = wv.y + ev.y; a2 = wv.z + ev.z; a3 = wv.w + ev.w;
        } else {
          a0 = (ng + 0 < N) ? W[grow + ng + 0] + E[grow + ng + 0] : 0;
          a1 = (ng + 1 < N) ? W[grow + ng + 1] + E[grow + ng + 1] : 0;
          a2 = (ng + 2 < N) ? W[grow + ng + 2] + E[grow + ng + 2] : 0;
          a3 = (ng + 3 < N) ? W[grow + ng + 3] + E[grow + ng + 3] : 0;
        }
        *(int*)(lin + k * 68 + nl) = pack4i(a0, a1, a2, a3);
      }
    }
  }
  __syncthreads();
  {
    const int n = t & 63, kq = t >> 6;
    char* dst = Bt + (long)(n0 + n) * K + k0 + (kq << 6);
    int outv[16];
    #pragma unroll
    for (int g = 0; g < 16; ++g) {
      const int k = (kq << 6) + (g << 2);
      outv[g] = pack4i(lin[(k + 0) * 68 + n], lin[(k + 1) * 68 + n],
                       lin[(k + 2) * 68 + n], lin[(k + 3) * 68 + n]);
    }
    #pragma unroll
    for (int g = 0; g < 4; ++g)
      *(int4*)(dst + (g << 4)) =
          make_int4(outv[g * 4], outv[g * 4 + 1], outv[g * 4 + 2], outv[g * 4 + 3]);
  }
}

// ---------------------------------------------------------------------------
// pack_all: weight tiles + biases + X (int32 -> int8, row-major, into d_out).
// ---------------------------------------------------------------------------
__global__ __launch_bounds__(256) void pack_all_kernel(
    const int* W1, const int* E1, char* Bt1,
    const int* W2, const int* E2, char* Bt2,
    const int* W3, const int* E3, char* Bt3,
    const int* b1, const int* eb1, int* bs1,
    const int* b2, const int* eb2, int* bs2,
    const int* b3, const int* eb3, int* bs3,
    const int* X, char* X8) {
  __shared__ __align__(16) char lin[256 * 68];
  const int bid = blockIdx.x;
  if (bid < 192) {
    pack_tile(W1, E1, Bt1, 3072, 1024, bid % 16, bid / 16, lin);
  } else if (bid < 256) {
    const int l = bid - 192;
    pack_tile(W2, E2, Bt2, 1024, 1024, l % 16, l / 16, lin);
  } else if (bid < 264) {
    const int l = bid - 256;
    pack_tile(W3, E3, Bt3, 1024, 100, l & 1, l >> 1, lin);
  } else if (bid == 264) {
    const int t = threadIdx.x;
    for (int i = t; i < 1024; i += 256) {
      bs1[i] = b1[i] + eb1[i];
      bs2[i] = b2[i] + eb2[i];
    }
    for (int i = t; i < 128; i += 256)
      bs3[i] = (i < 100) ? (b3[i] + eb3[i]) : 0;
  } else {
    // X pack: 1024 blocks, each 24576 ints; thread handles 16 ints/iter x 6.
    const int b = bid - 265;
    const long base = (long)b * 24576;
    const int t = threadIdx.x;
    #pragma unroll
    for (int i = 0; i < 6; ++i) {
      const long i0 = base + ((long)(t + i * 256) << 4);
      const int* src = X + i0;
      int4 v0 = *(const int4*)(src);
      int4 v1 = *(const int4*)(src + 4);
      int4 v2 = *(const int4*)(src + 8);
      int4 v3 = *(const int4*)(src + 12);
      *(int4*)(X8 + i0) = make_int4(
          pack4i(v0.x, v0.y, v0.z, v0.w), pack4i(v1.x, v1.y, v1.z, v1.w),
          pack4i(v2.x, v2.y, v2.z, v2.w), pack4i(v3.x, v3.y, v3.z, v3.w));
    }
  }
}

// ---------------------------------------------------------------------------
// GEMM: C = trunc_i8(A8 @ Bt^T + bsum [+ H]) ; 128x128 tile, BK=64, 256 thr.
// A is int8 [M][K]. 2-stage LDS double buffer; prefetch = 16 VGPRs only.
// ---------------------------------------------------------------------------
template<bool DO_HADD, bool DO_I8OUT, bool DO_IOUT>
__global__ __launch_bounds__(256, 2) void gemm_kernel(
    const char* __restrict__ A, const char* __restrict__ Btg,
    const int* __restrict__ bsum, const int* __restrict__ Hadd,
    char* __restrict__ A8out, int* __restrict__ Iout, const int K) {
  // stage: As [128][80] (10240) + Bs [128][80] (10240) = 20480 B
  __shared__ __align__(16) char smem[40960];

  const int t = threadIdx.x;
  const int mt = blockIdx.x & 63;   // same-A blocks land on same XCD (bid%8 const)
  const int nt = blockIdx.x >> 6;
  const long m0 = (long)mt << 7;
  const int n0 = nt << 7;

  const int lane = t & 63, w = t >> 6;
  const int wm = w & 1, wn = w >> 1;
  const int lc = lane & 31, hg = lane >> 5;

  v16i acc[2][2] = {};

  const int sm = t >> 1, sh = t & 1;
  const char* Arow = A + (m0 + sm) * (long)K + sh * 32;
  const char* Brow = Btg + (long)(n0 + sm) * K + sh * 32;
  const int soff = sm * 80 + sh * 32;

  const int abo = (wm * 64 + lc) * 80 + hg * 16;
  const int bbo = (wn * 64 + lc) * 80 + hg * 16;

  int4 ar[2], br[2];
  auto LOAD = [&](int kb) {
    ar[0] = *(const int4*)(Arow + kb);
    ar[1] = *(const int4*)(Arow + kb + 16);
    br[0] = *(const int4*)(Brow + kb);
    br[1] = *(const int4*)(Brow + kb + 16);
  };
  auto STORE = [&](int stage) {
    char* As_ = smem + stage * 20480;
    char* Bs_ = As_ + 10240;
    *(int4*)(As_ + soff)      = ar[0];
    *(int4*)(As_ + soff + 16) = ar[1];
    *(int4*)(Bs_ + soff)      = br[0];
    *(int4*)(Bs_ + soff + 16) = br[1];
  };

  const int kiters = K >> 6;
  LOAD(0);
  STORE(0);
  __syncthreads();

  for (int kt = 0; kt < kiters; ++kt) {
    if (kt + 1 < kiters) LOAD((kt + 1) << 6);   // in flight during MFMA
    const char* base = smem + (kt & 1) * 20480;
    const char* Ab = base + abo;
    const char* Bb = base + 10240 + bbo;
    #pragma unroll
    for (int ks = 0; ks < 2; ++ks) {
      v4i a0 = *(const v4i*)(Ab + ks * 32);
      v4i a1 = *(const v4i*)(Ab + 32 * 80 + ks * 32);
      v4i b0 = *(const v4i*)(Bb + ks * 32);
      v4i b1 = *(const v4i*)(Bb + 32 * 80 + ks * 32);
      acc[0][0] = __builtin_amdgcn_mfma_i32_32x32x32_i8(a0, b0, acc[0][0], 0, 0, 0);
      acc[0][1] = __builtin_amdgcn_mfma_i32_32x32x32_i8(a0, b1, acc[0][1], 0, 0, 0);
      acc[1][0] = __builtin_amdgcn_mfma_i32_32x32x32_i8(a1, b0, acc[1][0], 0, 0, 0);
      acc[1][1] = __builtin_amdgcn_mfma_i32_32x32x32_i8(a1, b1, acc[1][1], 0, 0, 0);
    }
    if (kt + 1 < kiters) {
      STORE((kt + 1) & 1);   // buffer fenced by previous barrier
      __syncthreads();
    }
  }

  // Epilogue. C/D layout: col = lane&31, row = (reg&3) + 8*(reg>>2) + 4*hg.
  if (DO_I8OUT) __syncthreads();
  const int bsv[2] = { bsum[n0 + wn * 64 + lc], bsum[n0 + wn * 64 + 32 + lc] };
  #pragma unroll
  for (int tm = 0; tm < 2; ++tm) {
    #pragma unroll
    for (int tn = 0; tn < 2; ++tn) {
      const int gcl = wn * 64 + tn * 32 + lc;
      const long gc = n0 + gcl;
      #pragma unroll
      for (int r = 0; r < 16; ++r) {
        const int lrow = wm * 64 + tm * 32 + (hg << 2) + (r & 3) + ((r >> 2) << 3);
        const long gm = m0 + lrow;
        int v = acc[tm][tn][r] + bsv[tn];
        if (DO_HADD) v += Hadd[gm * 1024 + gc];
        const int b8 = (int)(signed char)v;   // mod-256 truncate, sign-extend
        if (DO_I8OUT) smem[lrow * 144 + gcl] = (char)b8;
        if (DO_IOUT) Iout[gm * 1024 + gc] = b8;
      }
    }
  }
  if (DO_I8OUT) {
    __syncthreads();
    const char* src = smem + sm * 144 + sh * 64;
    char* dst = A8out + ((m0 + sm) << 10) + n0 + sh * 64;
    #pragma unroll
    for (int g = 0; g < 4; ++g)
      *(int4*)(dst + (g << 4)) = *(const int4*)(src + (g << 4));
  }
}

// ---------------------------------------------------------------------------
// Layer 3: 32x128 tile (256 blocks), K=1024, A = h2 int32 from d_out.
// ---------------------------------------------------------------------------
__global__ __launch_bounds__(256, 2) void gemm3_kernel(
    const int* __restrict__ h2, const char* __restrict__ Btg,
    const int* __restrict__ bsum, int* __restrict__ Iout) {
  __shared__ __align__(16) char smem[25600];
  const int t = threadIdx.x;
  const int m0 = blockIdx.x << 5;
  const int lane = t & 63, w = t >> 6;
  const int lc = lane & 31, hg = lane >> 5;
  v16i acc = {};

  const int am = t >> 3, ah = t & 7;
  const long arow = (long)(m0 + am) * 1024 + ah * 8;
  const int aoff = am * 80 + ah * 8;
  const int bm = t >> 1, bh = t & 1;
  const char* Brow = Btg + (long)bm * 1024 + bh * 32;
  const int boff = bm * 80 + bh * 32;

  int4 ar[2]; int4 br[2];
  auto LOAD = [&](int kb) {
    const int* Ar = h2 + arow + kb;
    ar[0] = *(const int4*)(Ar);
    ar[1] = *(const int4*)(Ar + 4);
    br[0] = *(const int4*)(Brow + kb);
    br[1] = *(const int4*)(Brow + kb + 16);
  };
  auto STORE = [&](int stage) {
    char* As_ = smem + stage * 12800;
    char* Bs_ = As_ + 2560;
    int2 d;
    d.x = pack4i(ar[0].x, ar[0].y, ar[0].z, ar[0].w);
    d.y = pack4i(ar[1].x, ar[1].y, ar[1].z, ar[1].w);
    *(int2*)(As_ + aoff) = d;
    *(int4*)(Bs_ + boff)      = br[0];
    *(int4*)(Bs_ + boff + 16) = br[1];
  };

  LOAD(0); STORE(0); __syncthreads();
  for (int kt = 0; kt < 16; ++kt) {
    if (kt + 1 < 16) LOAD((kt + 1) << 6);
    const char* base = smem + (kt & 1) * 12800;
    const char* Ab = base + lc * 80 + hg * 16;
    const char* Bb = base + 2560 + (w * 32 + lc) * 80 + hg * 16;
    #pragma unroll
    for (int ks = 0; ks < 2; ++ks) {
      v4i a = *(const v4i*)(Ab + ks * 32);
      v4i b = *(const v4i*)(Bb + ks * 32);
      acc = __builtin_amdgcn_mfma_i32_32x32x32_i8(a, b, acc, 0, 0, 0);
    }
    if (kt + 1 < 16) { STORE((kt + 1) & 1); __syncthreads(); }
  }

  const int gcl = w * 32 + lc;
  if (gcl < 100) {
    const int bs = bsum[gcl];
    #pragma unroll
    for (int r = 0; r < 16; ++r) {
      const int row = (r & 3) + ((r >> 2) << 3) + (hg << 2);
      Iout[(long)(m0 + row) * 100 + gcl] = (int)(signed char)(acc[r] + bs);
    }
  }
}

// ---------------------------------------------------------------------------
// ws (12.7 MB): Bt1 | Bt2 | Bt3 | bs1 | bs2 | bs3 | A2
// X8 (25.2 MB int8) lives in d_out[0..25.2MB) — dead before L2 writes h2 there.
// ---------------------------------------------------------------------------
extern "C" void kernel_launch(void* const* d_in, const int* in_sizes, int n_in,
                              void* d_out, int out_size, void* d_ws, size_t ws_size,
                              hipStream_t stream) {
  (void)in_sizes; (void)n_in; (void)out_size; (void)ws_size;
  const int* W1  = (const int*)d_in[0];
  const int* b1  = (const int*)d_in[1];
  const int* W2  = (const int*)d_in[2];
  const int* b2  = (const int*)d_in[3];
  const int* W3  = (const int*)d_in[4];
  const int* b3  = (const int*)d_in[5];
  const int* E1  = (const int*)d_in[6];
  const int* eb1 = (const int*)d_in[7];
  const int* E2  = (const int*)d_in[8];
  const int* eb2 = (const int*)d_in[9];
  const int* E3  = (const int*)d_in[10];
  const int* eb3 = (const int*)d_in[11];
  const int* X   = (const int*)d_in[12];   // [8192][3072] int32
  const int* H   = (const int*)d_in[13];   // [8192][1024] int32
  int* out = (int*)d_out;                  // h2 [8192*1024] then out [8192*100]

  char* ws  = (char*)d_ws;
  char* Bt1 = ws;                          // 3,145,728
  char* Bt2 = Bt1 + 3145728;               // 1,048,576
  char* Bt3 = Bt2 + 1048576;               //   131,072 (rows 100..127 zeroed)
  int*  bs1 = (int*)(Bt3 + 131072);        // 1024 ints
  int*  bs2 = bs1 + 1024;                  // 1024 ints
  int*  bs3 = bs2 + 1024;                  //  128 ints
  char* A2  = (char*)(bs3 + 128);          // 8,388,608 int8
  char* X8  = (char*)d_out;                // 25,165,824 int8 (temp, in d_out)

  pack_all_kernel<<<dim3(1289), dim3(256), 0, stream>>>(
      W1, E1, Bt1, W2, E2, Bt2, W3, E3, Bt3,
      b1, eb1, bs1, b2, eb2, bs2, b3, eb3, bs3, X, X8);

  // Layer 1: i2c fused with hiddens-add -> A2 (int8)
  gemm_kernel<true, true, false><<<dim3(512), dim3(256), 0, stream>>>(
      X8, Bt1, bs1, H, A2, nullptr, 3072);

  // Layer 2: h2 -> d_out (int32)
  gemm_kernel<false, false, true><<<dim3(512), dim3(256), 0, stream>>>(
      A2, Bt2, bs2, nullptr, nullptr, out, 1024);

  // Layer 3: reads h2 from d_out (int32), writes out region (int32)
  gemm3_kernel<<<dim3(256), dim3(256), 0, stream>>>(
      out, Bt3, bs3, out + 8388608);
}

// Round 5
// 315.197 us; speedup vs baseline: 1.2949x; 1.2697x over previous
//
#include <hip/hip_runtime.h>

typedef int v4i  __attribute__((ext_vector_type(4)));
typedef int v16i __attribute__((ext_vector_type(16)));

__device__ __forceinline__ int pack4i(int a, int b, int c, int d) {
  return (a & 255) | ((b & 255) << 8) | ((c & 255) << 16) | ((d & 255) << 24);
}
// SWAR per-byte add (mod-256 per lane-byte)
__device__ __forceinline__ int badd4(int a, int b) {
  return ((a & 0x7f7f7f7f) + (b & 0x7f7f7f7f)) ^ ((a ^ b) & 0x80808080);
}

// ---------------------------------------------------------------------------
// Pack (W + E) -> int8, transposed Bt[n][k] (row stride K bytes).
// Tile: 64 n x 256 k per block, 256 threads. Zero-pads n >= N rows.
// ---------------------------------------------------------------------------
__device__ void pack_tile(const int* __restrict__ W, const int* __restrict__ E,
                          char* __restrict__ Bt, int K, int N,
                          int nx, int ky, char* lin) {
  const int t = threadIdx.x;
  const int n0 = nx * 64, k0 = ky * 256;
  {
    const int kk = t >> 2, c = t & 3;
    for (int p = 0; p < 4; ++p) {
      const int k = kk + (p << 6);
      const long grow = (long)(k0 + k) * N;
      #pragma unroll
      for (int i = 0; i < 4; ++i) {
        const int nl = (c << 4) + (i << 2);
        const int ng = n0 + nl;
        int a0, a1, a2, a3;
        if (ng + 3 < N) {
          int4 wv = *(const int4*)(W + grow + ng);
          int4 ev = *(const int4*)(E + grow + ng);
          a0 = wv.x + ev.x; a1 = wv.y + ev.y; a2 = wv.z + ev.z; a3 = wv.w + ev.w;
        } else {
          a0 = (ng + 0 < N) ? W[grow + ng + 0] + E[grow + ng + 0] : 0;
          a1 = (ng + 1 < N) ? W[grow + ng + 1] + E[grow + ng + 1] : 0;
          a2 = (ng + 2 < N) ? W[grow + ng + 2] + E[grow + ng + 2] : 0;
          a3 = (ng + 3 < N) ? W[grow + ng + 3] + E[grow + ng + 3] : 0;
        }
        *(int*)(lin + k * 68 + nl) = pack4i(a0, a1, a2, a3);
      }
    }
  }
  __syncthreads();
  {
    const int n = t & 63, kq = t >> 6;
    char* dst = Bt + (long)(n0 + n) * K + k0 + (kq << 6);
    int outv[16];
    #pragma unroll
    for (int g = 0; g < 16; ++g) {
      const int k = (kq << 6) + (g << 2);
      outv[g] = pack4i(lin[(k + 0) * 68 + n], lin[(k + 1) * 68 + n],
                       lin[(k + 2) * 68 + n], lin[(k + 3) * 68 + n]);
    }
    #pragma unroll
    for (int g = 0; g < 4; ++g)
      *(int4*)(dst + (g << 4)) =
          make_int4(outv[g * 4], outv[g * 4 + 1], outv[g * 4 + 2], outv[g * 4 + 3]);
  }
}

__device__ void pack_i32_to_i8(const int* __restrict__ src, char* __restrict__ dst,
                               long base, int iters) {
  const int t = threadIdx.x;
  for (int i = 0; i < iters; ++i) {
    const long i0 = base + ((long)(t + i * 256) << 4);
    const int* s = src + i0;
    int4 v0 = *(const int4*)(s);
    int4 v1 = *(const int4*)(s + 4);
    int4 v2 = *(const int4*)(s + 8);
    int4 v3 = *(const int4*)(s + 12);
    *(int4*)(dst + i0) = make_int4(
        pack4i(v0.x, v0.y, v0.z, v0.w), pack4i(v1.x, v1.y, v1.z, v1.w),
        pack4i(v2.x, v2.y, v2.z, v2.w), pack4i(v3.x, v3.y, v3.z, v3.w));
  }
}

// ---------------------------------------------------------------------------
// pack_all: weight tiles + biases + X->X8 + H->H8 (into d_out scratch region).
// ---------------------------------------------------------------------------
__global__ __launch_bounds__(256) void pack_all_kernel(
    const int* W1, const int* E1, char* Bt1,
    const int* W2, const int* E2, char* Bt2,
    const int* W3, const int* E3, char* Bt3,
    const int* b1, const int* eb1, int* bs1,
    const int* b2, const int* eb2, int* bs2,
    const int* b3, const int* eb3, int* bs3,
    const int* X, char* X8, const int* H, char* H8) {
  __shared__ __align__(16) char lin[256 * 68];
  const int bid = blockIdx.x;
  if (bid < 192) {
    pack_tile(W1, E1, Bt1, 3072, 1024, bid % 16, bid / 16, lin);
  } else if (bid < 256) {
    const int l = bid - 192;
    pack_tile(W2, E2, Bt2, 1024, 1024, l % 16, l / 16, lin);
  } else if (bid < 264) {
    const int l = bid - 256;
    pack_tile(W3, E3, Bt3, 1024, 100, l & 1, l >> 1, lin);
  } else if (bid == 264) {
    const int t = threadIdx.x;
    for (int i = t; i < 1024; i += 256) {
      bs1[i] = b1[i] + eb1[i];
      bs2[i] = b2[i] + eb2[i];
    }
    for (int i = t; i < 128; i += 256)
      bs3[i] = (i < 100) ? (b3[i] + eb3[i]) : 0;
  } else if (bid < 1289) {
    // X: 25,165,824 ints; 1024 blocks x 24576 ints (6 iters of 16/thread)
    pack_i32_to_i8(X, X8, (long)(bid - 265) * 24576, 6);
  } else {
    // H: 8,388,608 ints; 256 blocks x 32768 ints (8 iters of 16/thread)
    pack_i32_to_i8(H, H8, (long)(bid - 1289) * 32768, 8);
  }
}

// ---------------------------------------------------------------------------
// GEMM: 64x128 tile, BK=64, 256 thr (4 waves, each 64x32), 2-stage LDS dbuf.
// Grid 1024 -> 4 blocks/CU, 16 waves/CU. mt = bid&127 so the 8 blocks sharing
// an A-tile are congruent mod 8 -> same XCD -> A re-reads hit that XCD's L2.
// EPI 0: A8out = trunc8(acc+bs) SWAR+ H8, int8, via LDS transpose  (layer 1)
// EPI 1: Iout  = trunc8(acc+bs) as int32, direct                   (layer 2)
// ---------------------------------------------------------------------------
template<int EPI>
__global__ __launch_bounds__(256, 4) void gemm_kernel(
    const char* __restrict__ A, const char* __restrict__ Btg,
    const int* __restrict__ bsum, const char* __restrict__ H8,
    char* __restrict__ A8out, int* __restrict__ Iout, const int K) {
  // stage: As [64][80] (5120) + Bs [128][80] (10240) = 15360; x2 = 30720
  __shared__ __align__(16) char smem[30720];

  const int t = threadIdx.x;
  const int bid = blockIdx.x;
  const int mt = bid & 127, nt = bid >> 7;
  const long m0 = (long)mt << 6;
  const int n0 = nt << 7;

  const int lane = t & 63, w = t >> 6;
  const int lc = lane & 31, hg = lane >> 5;

  v16i acc[2] = {};

  // A staging: 64 rows x 4 thr x 16B ; B staging: 128 rows x 2 thr x 32B
  const int am = t >> 2, ah = t & 3;
  const char* Arow = A + (m0 + am) * (long)K + ah * 16;
  const int aoff = am * 80 + ah * 16;
  const int bm = t >> 1, bh = t & 1;
  const char* Brow = Btg + (long)(n0 + bm) * K + bh * 32;
  const int boff = bm * 80 + bh * 32;

  const int abo = lc * 80 + hg * 16;               // + tm*32*80 + ks*32
  const int bbo = (w * 32 + lc) * 80 + hg * 16;    // + ks*32

  int4 ar, br0, br1;
  auto LOAD = [&](int kb) {
    ar  = *(const int4*)(Arow + kb);
    br0 = *(const int4*)(Brow + kb);
    br1 = *(const int4*)(Brow + kb + 16);
  };
  auto STORE = [&](int stage) {
    char* base = smem + stage * 15360;
    *(int4*)(base + aoff) = ar;
    *(int4*)(base + 5120 + boff)      = br0;
    *(int4*)(base + 5120 + boff + 16) = br1;
  };

  const int kiters = K >> 6;
  LOAD(0);
  STORE(0);
  __syncthreads();

  for (int kt = 0; kt < kiters; ++kt) {
    if (kt + 1 < kiters) LOAD((kt + 1) << 6);   // in flight during MFMA
    const char* base = smem + (kt & 1) * 15360;
    const char* Ab = base + abo;
    const char* Bb = base + 5120 + bbo;
    #pragma unroll
    for (int ks = 0; ks < 2; ++ks) {
      v4i a0 = *(const v4i*)(Ab + ks * 32);
      v4i a1 = *(const v4i*)(Ab + 32 * 80 + ks * 32);
      v4i b  = *(const v4i*)(Bb + ks * 32);
      acc[0] = __builtin_amdgcn_mfma_i32_32x32x32_i8(a0, b, acc[0], 0, 0, 0);
      acc[1] = __builtin_amdgcn_mfma_i32_32x32x32_i8(a1, b, acc[1], 0, 0, 0);
    }
    if (kt + 1 < kiters) {
      STORE((kt + 1) & 1);   // buffer fenced by previous barrier
      __syncthreads();
    }
  }

  // Epilogue. C/D layout: col = lane&31, row = (reg&3) + 8*(reg>>2) + 4*hg.
  const int gcl = w * 32 + lc;
  const int bs = bsum[n0 + gcl];
  if (EPI == 1) {
    #pragma unroll
    for (int tm = 0; tm < 2; ++tm) {
      #pragma unroll
      for (int r = 0; r < 16; ++r) {
        const int row = tm * 32 + (hg << 2) + (r & 3) + ((r >> 2) << 3);
        Iout[(m0 + row) * 1024 + n0 + gcl] = (int)(signed char)(acc[tm][r] + bs);
      }
    }
  } else {
    __syncthreads();   // smem reused as 64x144 transpose buffer
    #pragma unroll
    for (int tm = 0; tm < 2; ++tm) {
      #pragma unroll
      for (int r = 0; r < 16; ++r) {
        const int row = tm * 32 + (hg << 2) + (r & 3) + ((r >> 2) << 3);
        smem[row * 144 + gcl] = (char)(acc[tm][r] + bs);
      }
    }
    __syncthreads();
    // readout: thread -> row t>>2, 32 bytes at (t&3)*32 ; SWAR-add H8
    const char* src = smem + (t >> 2) * 144 + (t & 3) * 32;
    const long gm = m0 + (t >> 2);
    const long gco = gm * 1024 + n0 + (t & 3) * 32;
    int4 s0 = *(const int4*)(src);
    int4 s1 = *(const int4*)(src + 16);
    int4 h0 = *(const int4*)(H8 + gco);
    int4 h1 = *(const int4*)(H8 + gco + 16);
    s0 = make_int4(badd4(s0.x, h0.x), badd4(s0.y, h0.y),
                   badd4(s0.z, h0.z), badd4(s0.w, h0.w));
    s1 = make_int4(badd4(s1.x, h1.x), badd4(s1.y, h1.y),
                   badd4(s1.z, h1.z), badd4(s1.w, h1.w));
    *(int4*)(A8out + gco)      = s0;
    *(int4*)(A8out + gco + 16) = s1;
  }
}

// ---------------------------------------------------------------------------
// Layer 3: 32x128 tile (256 blocks), K=1024, A = h2 int32 from d_out.
// ---------------------------------------------------------------------------
__global__ __launch_bounds__(256, 2) void gemm3_kernel(
    const int* __restrict__ h2, const char* __restrict__ Btg,
    const int* __restrict__ bsum, int* __restrict__ Iout) {
  __shared__ __align__(16) char smem[25600];
  const int t = threadIdx.x;
  const int m0 = blockIdx.x << 5;
  const int lane = t & 63, w = t >> 6;
  const int lc = lane & 31, hg = lane >> 5;
  v16i acc = {};

  const int am = t >> 3, ah = t & 7;
  const long arow = (long)(m0 + am) * 1024 + ah * 8;
  const int aoff = am * 80 + ah * 8;
  const int bm = t >> 1, bh = t & 1;
  const char* Brow = Btg + (long)bm * 1024 + bh * 32;
  const int boff = bm * 80 + bh * 32;

  int4 ar[2]; int4 br[2];
  auto LOAD = [&](int kb) {
    const int* Ar = h2 + arow + kb;
    ar[0] = *(const int4*)(Ar);
    ar[1] = *(const int4*)(Ar + 4);
    br[0] = *(const int4*)(Brow + kb);
    br[1] = *(const int4*)(Brow + kb + 16);
  };
  auto STORE = [&](int stage) {
    char* As_ = smem + stage * 12800;
    char* Bs_ = As_ + 2560;
    int2 d;
    d.x = pack4i(ar[0].x, ar[0].y, ar[0].z, ar[0].w);
    d.y = pack4i(ar[1].x, ar[1].y, ar[1].z, ar[1].w);
    *(int2*)(As_ + aoff) = d;
    *(int4*)(Bs_ + boff)      = br[0];
    *(int4*)(Bs_ + boff + 16) = br[1];
  };

  LOAD(0); STORE(0); __syncthreads();
  for (int kt = 0; kt < 16; ++kt) {
    if (kt + 1 < 16) LOAD((kt + 1) << 6);
    const char* base = smem + (kt & 1) * 12800;
    const char* Ab = base + lc * 80 + hg * 16;
    const char* Bb = base + 2560 + (w * 32 + lc) * 80 + hg * 16;
    #pragma unroll
    for (int ks = 0; ks < 2; ++ks) {
      v4i a = *(const v4i*)(Ab + ks * 32);
      v4i b = *(const v4i*)(Bb + ks * 32);
      acc = __builtin_amdgcn_mfma_i32_32x32x32_i8(a, b, acc, 0, 0, 0);
    }
    if (kt + 1 < 16) { STORE((kt + 1) & 1); __syncthreads(); }
  }

  const int gcl = w * 32 + lc;
  if (gcl < 100) {
    const int bs = bsum[gcl];
    #pragma unroll
    for (int r = 0; r < 16; ++r) {
      const int row = (r & 3) + ((r >> 2) << 3) + (hg << 2);
      Iout[(long)(m0 + row) * 100 + gcl] = (int)(signed char)(acc[r] + bs);
    }
  }
}

// ---------------------------------------------------------------------------
// ws (12.7 MB): Bt1 | Bt2 | Bt3 | bs1 | bs2 | bs3 | A2
// d_out scratch: X8 [0,25.2M) + H8 [25.2M,33.6M) — both dead before L2
// overwrites the region with h2 (launch order on one stream guarantees it).
// ---------------------------------------------------------------------------
extern "C" void kernel_launch(void* const* d_in, const int* in_sizes, int n_in,
                              void* d_out, int out_size, void* d_ws, size_t ws_size,
                              hipStream_t stream) {
  (void)in_sizes; (void)n_in; (void)out_size; (void)ws_size;
  const int* W1  = (const int*)d_in[0];
  const int* b1  = (const int*)d_in[1];
  const int* W2  = (const int*)d_in[2];
  const int* b2  = (const int*)d_in[3];
  const int* W3  = (const int*)d_in[4];
  const int* b3  = (const int*)d_in[5];
  const int* E1  = (const int*)d_in[6];
  const int* eb1 = (const int*)d_in[7];
  const int* E2  = (const int*)d_in[8];
  const int* eb2 = (const int*)d_in[9];
  const int* E3  = (const int*)d_in[10];
  const int* eb3 = (const int*)d_in[11];
  const int* X   = (const int*)d_in[12];   // [8192][3072] int32
  const int* H   = (const int*)d_in[13];   // [8192][1024] int32
  int* out = (int*)d_out;                  // h2 [8192*1024] then out [8192*100]

  char* ws  = (char*)d_ws;
  char* Bt1 = ws;                          // 3,145,728
  char* Bt2 = Bt1 + 3145728;               // 1,048,576
  char* Bt3 = Bt2 + 1048576;               //   131,072 (rows 100..127 zeroed)
  int*  bs1 = (int*)(Bt3 + 131072);        // 1024 ints
  int*  bs2 = bs1 + 1024;                  // 1024 ints
  int*  bs3 = bs2 + 1024;                  //  128 ints
  char* A2  = (char*)(bs3 + 128);          // 8,388,608 int8
  char* X8  = (char*)d_out;                // 25,165,824 int8 (temp in d_out)
  char* H8  = X8 + 25165824;               //  8,388,608 int8 (temp in d_out)

  pack_all_kernel<<<dim3(1545), dim3(256), 0, stream>>>(
      W1, E1, Bt1, W2, E2, Bt2, W3, E3, Bt3,
      b1, eb1, bs1, b2, eb2, bs2, b3, eb3, bs3, X, X8, H, H8);

  // Layer 1: i2c + hiddens-add -> A2 (int8)
  gemm_kernel<0><<<dim3(1024), dim3(256), 0, stream>>>(
      X8, Bt1, bs1, H8, A2, nullptr, 3072);

  // Layer 2: h2 -> d_out (int32)
  gemm_kernel<1><<<dim3(1024), dim3(256), 0, stream>>>(
      A2, Bt2, bs2, nullptr, nullptr, out, 1024);

  // Layer 3: reads h2 from d_out (int32), writes out region (int32)
  gemm3_kernel<<<dim3(256), dim3(256), 0, stream>>>(
      out, Bt3, bs3, out + 8388608);
}